// Round 1
// 102.850 us; speedup vs baseline: 1.0117x; 1.0117x over previous
//
#include <hip/hip_runtime.h>

// (B,H,W,D) = (4,128,128,128) fp32, row-major, D innermost.
// R = -2*exp(-2*Phi) * (lap + 2*|grad Phi|^2), Phi = pos - lam*neg, edge-clamped, h=1.
//
// R5: 2x2 (H,W) register blocking. Each thread computes 4 outputs (one float4
// along D at (h0,w0),(h0,w1),(h1,w0),(h1,w1)). The 4 centers serve as each
// other's x/y neighbors, so global loads drop from 10 to 6 per output
// (24 loads for 4 outputs): -40% L1/L2 request traffic at identical HBM bytes.
// z-direction still via cross-lane shfl (lane = dvec & 31, same rows per lane
// group), clamped at dvec 0/31.
//
// History: R3 nontemporal store regressed (107.8->115.1). R4 (prev best, 104.0)
// was 1 output/thread, 10 loads/output.

typedef float vfloat4 __attribute__((ext_vector_type(4)));

#define NTHREADS (4 * 64 * 64 * 32)   // 524288 threads, 4 outputs each

__device__ __forceinline__ vfloat4 stencil_out(
    const vfloat4 c, const vfloat4 xpv, const vfloat4 xmv,
    const vfloat4 ypv, const vfloat4 ymv, const int dvec)
{
    // z-edge neighbors via cross-lane shuffle: lane L-1 holds the same
    // (b,h,w) row at dvec-1 (lane = dvec within each 32-lane half-wave).
    const float fu = __shfl_up(c.w, 1);     // garbage at dvec==0 — clamped
    const float fd = __shfl_down(c.x, 1);   // garbage at dvec==31 — clamped
    const float left  = (dvec > 0)  ? fu : c.x;   // d=-1 clamps to d=0
    const float right = (dvec < 31) ? fd : c.w;   // d=128 clamps to d=127

    const float cc[4]  = { c.x, c.y, c.z, c.w };
    const float zl[4]  = { left, c.x, c.y, c.z };
    const float zr[4]  = { c.y, c.z, c.w, right };
    const float xpa[4] = { xpv.x, xpv.y, xpv.z, xpv.w };
    const float xma[4] = { xmv.x, xmv.y, xmv.z, xmv.w };
    const float ypa[4] = { ypv.x, ypv.y, ypv.z, ypv.w };
    const float yma[4] = { ymv.x, ymv.y, ymv.z, ymv.w };

    vfloat4 o;
#pragma unroll
    for (int j = 0; j < 4; ++j) {
        const float gx = (xpa[j] - xma[j]) * 0.5f;
        const float gy = (ypa[j] - yma[j]) * 0.5f;
        const float gz = (zr[j]  - zl[j])  * 0.5f;
        const float grad_sq = gx * gx + gy * gy + gz * gz;
        const float lap = xpa[j] + xma[j] + ypa[j] + yma[j] + zl[j] + zr[j]
                          - 6.0f * cc[j];
        o[j] = -2.0f * __expf(-2.0f * cc[j]) * (lap + 2.0f * grad_sq);
    }
    return o;
}

__global__ __launch_bounds__(256, 4) void conformal_kernel(
    const float* __restrict__ pos, const float* __restrict__ neg,
    const float* __restrict__ lamp, float* __restrict__ out)
{
    const float lam = lamp[0];
    const int t = blockIdx.x * blockDim.x + threadIdx.x;

    const int dvec = t & 31;            // float4 index along D (32 per row)
    const int wp   = (t >> 5)  & 63;    // W pair index
    const int hp   = (t >> 11) & 63;    // H pair index
    const int b    = t >> 17;

    const int w0 = wp * 2, w1 = w0 + 1;
    const int h0 = hp * 2, h1 = h0 + 1;

    // Edge clamp: out-of-range neighbor folds back to the boundary row/plane.
    const int hxm = (h0 > 0)   ? h0 - 1 : 0;
    const int hxp = (h1 < 127) ? h1 + 1 : 127;
    const int wym = (w0 > 0)   ? w0 - 1 : 0;
    const int wyp = (w1 < 127) ? w1 + 1 : 127;

    // float4 linear index: ((b*128 + h)*128 + w)*32 + dvec
    const int base = ((b * 128 + h0) * 128 + w0) * 32 + dvec;
    const int i_c00 = base;                                   // (h0,w0)
    const int i_c01 = base + 32;                              // (h0,w1)
    const int i_c10 = base + 4096;                            // (h1,w0)
    const int i_c11 = base + 4096 + 32;                       // (h1,w1)
    const int i_xm0 = ((b * 128 + hxm) * 128 + w0) * 32 + dvec;
    const int i_xm1 = i_xm0 + 32;
    const int i_xp0 = ((b * 128 + hxp) * 128 + w0) * 32 + dvec;
    const int i_xp1 = i_xp0 + 32;
    const int i_ym0 = ((b * 128 + h0) * 128 + wym) * 32 + dvec;
    const int i_ym1 = i_ym0 + 4096;
    const int i_yp0 = ((b * 128 + h0) * 128 + wyp) * 32 + dvec;
    const int i_yp1 = i_yp0 + 4096;

    const vfloat4* posv = (const vfloat4*)pos;
    const vfloat4* negv = (const vfloat4*)neg;

    // Issue all 24 loads up front for maximum MLP.
    const vfloat4 p_c00 = posv[i_c00], n_c00 = negv[i_c00];
    const vfloat4 p_c01 = posv[i_c01], n_c01 = negv[i_c01];
    const vfloat4 p_c10 = posv[i_c10], n_c10 = negv[i_c10];
    const vfloat4 p_c11 = posv[i_c11], n_c11 = negv[i_c11];
    const vfloat4 p_xm0 = posv[i_xm0], n_xm0 = negv[i_xm0];
    const vfloat4 p_xm1 = posv[i_xm1], n_xm1 = negv[i_xm1];
    const vfloat4 p_xp0 = posv[i_xp0], n_xp0 = negv[i_xp0];
    const vfloat4 p_xp1 = posv[i_xp1], n_xp1 = negv[i_xp1];
    const vfloat4 p_ym0 = posv[i_ym0], n_ym0 = negv[i_ym0];
    const vfloat4 p_ym1 = posv[i_ym1], n_ym1 = negv[i_ym1];
    const vfloat4 p_yp0 = posv[i_yp0], n_yp0 = negv[i_yp0];
    const vfloat4 p_yp1 = posv[i_yp1], n_yp1 = negv[i_yp1];

    // Phi = pos - lam*neg at all 12 positions.
    const vfloat4 c00 = p_c00 - lam * n_c00;
    const vfloat4 c01 = p_c01 - lam * n_c01;
    const vfloat4 c10 = p_c10 - lam * n_c10;
    const vfloat4 c11 = p_c11 - lam * n_c11;
    const vfloat4 xm0 = p_xm0 - lam * n_xm0;
    const vfloat4 xm1 = p_xm1 - lam * n_xm1;
    const vfloat4 xp0 = p_xp0 - lam * n_xp0;
    const vfloat4 xp1 = p_xp1 - lam * n_xp1;
    const vfloat4 ym0 = p_ym0 - lam * n_ym0;
    const vfloat4 ym1 = p_ym1 - lam * n_ym1;
    const vfloat4 yp0 = p_yp0 - lam * n_yp0;
    const vfloat4 yp1 = p_yp1 - lam * n_yp1;

    vfloat4* outv = (vfloat4*)out;
    //                      center  xp    xm    yp    ym
    outv[i_c00] = stencil_out(c00,  c10,  xm0,  c01,  ym0, dvec);
    outv[i_c01] = stencil_out(c01,  c11,  xm1,  yp0,  c00, dvec);
    outv[i_c10] = stencil_out(c10,  xp0,  c00,  c11,  ym1, dvec);
    outv[i_c11] = stencil_out(c11,  xp1,  c01,  yp1,  c10, dvec);
}

extern "C" void kernel_launch(void* const* d_in, const int* in_sizes, int n_in,
                              void* d_out, int out_size, void* d_ws, size_t ws_size,
                              hipStream_t stream) {
    const float* pos = (const float*)d_in[0];
    const float* neg = (const float*)d_in[1];
    const float* lam = (const float*)d_in[2];
    float* out = (float*)d_out;

    const int threads = 256;
    const int blocks  = NTHREADS / threads;  // 2048
    conformal_kernel<<<blocks, threads, 0, stream>>>(pos, neg, lam, out);
}